// Round 14
// baseline (5087.268 us; speedup 1.0000x reference)
//
#include <hip/hip_runtime.h>

// Seq2Seq LSTM forecaster: H=256, B=256, S=672, T=96.
// Round 14: r11 base (3.20ms) + split per-wave flags to shorten the h0 recurrence.
//   - r13 lesson: conflicts -33% but time +3% -> LDS bank conflicts NOT critical;
//     reverted to r11 staging. Critical path = RT chain + what the single flag carries.
//   - f0 (h0 ready): per-wave publish right after h0 store+drain, NO barrier ->
//     peers' next tick starts while this wg computes layer1.
//   - f1 (h1 ready): h1 store left in flight; drained by the NEXT poll's first
//     vmcnt(0) (free), then published at poll entry. Second drain off the chain.
//   - wi1*a0 MFMAs issued between h0 store and its drain (hidden under drain).
//   - feat load overlapped with poll; hot-spin poll.
//   - Hazards re-verified: staging writes@t+1 gated by fe0>=t+1 (peers' a0 reads
//     done: publish follows MFMA0) and fe1>=t (peers entered t+1: a1 reads done).
//   - Decoder: r11 EXACT (3-phase wg-flag protocol, 0.63ms).

#define S_LEN 672
#define T_LEN 96
#define HDIM  256
#define SPIN_MAX (1 << 14)

typedef short short8 __attribute__((ext_vector_type(8)));
typedef float f32x4  __attribute__((ext_vector_type(4)));
typedef unsigned short u16;

// ---- workspace layout (bytes) ----
#define OFF_FLAG 0                                  // dtype mode flag
#define OFF_FE0  1024                               // enc f0: u32 [16g][64 wave]
#define OFF_FE1  (OFF_FE0 + 4096)                   // enc f1: u32 [16g][64 wave]
#define OFF_FD   (OFF_FE1 + 4096)                   // dec flags: [16g][16wg] u32 @32B
#define OFF_PART (OFF_FD + 16*16*32)                // f32 [2][16g][16m][16b]
#define ZERO_END (OFF_PART + 2*16*256*4)
#define OFF_H0   ZERO_END                           // u16 [16g][2][16b][256ch]
#define OFF_H1   (OFF_H0 + 16*2*4096*2)
#define OFF_F0   (OFF_H1 + 16*2*4096*2)             // u16 [16g][16b][256ch] h0 final
#define OFF_F1   (OFF_F0 + 16*4096*2)               // u16 h1 final
#define OFF_C0   (OFF_F1 + 16*4096*2)               // f32 [256][256]
#define OFF_C1   (OFF_C0 + 256*256*4)

__device__ __forceinline__ unsigned short f2bf(float f) {
  unsigned u = __float_as_uint(f);
  u += 0x7FFFu + ((u >> 16) & 1u);
  return (unsigned short)(u >> 16);
}
__device__ __forceinline__ float bf2f(unsigned short s) {
  return __uint_as_float(((unsigned)s) << 16);
}
__device__ __forceinline__ float ld_scalar(const void* p, long idx, int mode) {
  if (mode) return bf2f(((const u16*)p)[idx]);
  return ((const float*)p)[idx];
}
__device__ __forceinline__ short8 ld_frag8(const void* p, long row, long ld, long k0, int mode) {
  if (mode) {
    return *(const short8*)((const u16*)p + row * ld + k0);
  } else {
    const float* f = (const float*)p + row * ld + k0;
    short8 r;
#pragma unroll
    for (int i = 0; i < 8; i++) r[i] = (short)f2bf(f[i]);
    return r;
  }
}
__device__ __forceinline__ void st_out(void* out, size_t idx, float v, int mode) {
  if (mode) ((u16*)out)[idx] = f2bf(v);
  else      ((float*)out)[idx] = v;
}
__device__ __forceinline__ float sigm(float x) { return 1.f / (1.f + __expf(-x)); }

__device__ __forceinline__ f32x4 mfma_bf16(short8 a, short8 b, f32x4 c) {
  return __builtin_amdgcn_mfma_f32_16x16x32_bf16(a, b, c, 0, 0, 0);
}

// ---- system-scope data plane (sc0 sc1; r6/r7/r11-proven) ----
__device__ __forceinline__ void ld32B(const u16* b, short8* c0, short8* c1) {
  asm volatile(
    "global_load_dwordx4 %0, %2, off sc0 sc1\n\t"
    "global_load_dwordx4 %1, %2, off offset:16 sc0 sc1"
    : "=&v"(*c0), "=&v"(*c1) : "v"(b) : "memory");
}
__device__ __forceinline__ void issue2(const u16* base, short8* t) {
  asm volatile(
    "global_load_dwordx4 %0, %2, off sc0 sc1\n\t"
    "global_load_dwordx4 %1, %2, off offset:64 sc0 sc1"
    : "=&v"(t[0]), "=&v"(t[1]) : "v"(base) : "memory");
}
__device__ __forceinline__ void st16(u16* p, unsigned short v) {
  asm volatile("global_store_short %0, %1, off sc0 sc1"
               :: "v"(p), "v"((unsigned)v) : "memory");
}
__device__ __forceinline__ void st32(unsigned* p, unsigned v) {
  asm volatile("global_store_dword %0, %1, off sc0 sc1" :: "v"(p), "v"(v) : "memory");
}
__device__ __forceinline__ void stf32(float* p, float v) {
  asm volatile("global_store_dword %0, %1, off sc0 sc1" :: "v"(p), "v"(v) : "memory");
}
__device__ __forceinline__ float ldf32(const float* p) {
  float v;
  asm volatile("global_load_dword %0, %1, off sc0 sc1\n\ts_waitcnt vmcnt(0)"
               : "=&v"(v) : "v"(p) : "memory");
  __builtin_amdgcn_sched_barrier(0);
  return v;
}
__device__ __forceinline__ void waitv0() {
  asm volatile("s_waitcnt vmcnt(0)" ::: "memory");
  __builtin_amdgcn_sched_barrier(0);
}

// ---- dec control plane (r11 verbatim): wg flags @32B sectors ----
__device__ __forceinline__ void wg_publish(unsigned* fa, unsigned e) {
  asm volatile("s_waitcnt vmcnt(0)" ::: "memory");
  __syncthreads();
  if (threadIdx.x == 0)
    asm volatile("global_store_dword %0, %1, off sc0 sc1" :: "v"(fa), "v"(e) : "memory");
}
__device__ __forceinline__ void pollge(const unsigned* flags, unsigned E) {
  const unsigned* addr = flags + (threadIdx.x & 15) * 8;
  int spin = 0;
  for (;;) {
    unsigned v;
    asm volatile("global_load_dword %0, %1, off sc0 sc1\n\ts_waitcnt vmcnt(0)"
                 : "=&v"(v) : "v"(addr) : "memory");
    if (__all(v >= E)) break;
    if (++spin > SPIN_MAX) break;
    __builtin_amdgcn_s_sleep(1);
  }
  __builtin_amdgcn_sched_barrier(0);
}

// ---- dtype detector ----
__global__ void detect_mode(const unsigned* __restrict__ feat, unsigned* __restrict__ flag) {
  const int t = threadIdx.x;
  int cnt = 0;
#pragma unroll
  for (int i = 0; i < 8; i++) {
    const unsigned wv = feat[t * 8 + i];
    const unsigned e = (wv >> 7) & 0xFFu;
    cnt += (e >= 100u && e <= 130u) ? 1 : 0;
  }
#pragma unroll
  for (int o = 32; o > 0; o >>= 1) cnt += __shfl_down(cnt, o, 64);
  if (t == 0) flag[0] = (cnt >= 256) ? 1u : 0u;
}

// ============================ encoder ============================
// Tick t: layer0 step t (t<672), layer1 step t-1 (t>=1).
// fe0[wave]=t+1 after that wave's h0(t) store drained (published mid-tick t).
// fe1[wave]=s+1 after h1(s) coherent (h1(s) stored at tick s+1; drained+published
// at tick s+2's poll entry). Tick-t reads: a0=h0(t-1) needs fe0>=t; a1=h1(t-2)
// needs fe1>=t-1. Slab parity as r11.
__global__ void __launch_bounds__(256, 1)
enc_kernel(const void* __restrict__ feat,
           const void* __restrict__ Wih0, const void* __restrict__ Whh0, const void* __restrict__ b0,
           const void* __restrict__ Wih1, const void* __restrict__ Whh1, const void* __restrict__ b1,
           char* __restrict__ ws) {
  const int mode = (int)*(const unsigned*)(ws + OFF_FLAG);
  const int tid  = threadIdx.x;
  const int lane = tid & 63;
  const int w    = tid >> 6;
  const int bId  = blockIdx.x;
  const int g    = (bId & 7) * 2 + ((bId >> 3) & 1);
  const int m    = bId >> 4;

  const int fcol = lane & 15;                // batch row
  const int kq   = lane >> 4;                // k-quarter / channel sub-index
  const int chq  = m * 16 + w * 4 + kq;      // this lane's pointwise channel
  const int bgl  = g * 16 + fcol;
  const int sr   = tid >> 4;                 // stage row (batch)
  const int sc2  = (tid & 15) * 2;           // stage col (short8 chunks)

  unsigned* fe0g = (unsigned*)(ws + OFF_FE0) + g * 64;
  unsigned* fe1g = (unsigned*)(ws + OFF_FE1) + g * 64;
  u16* h0s = (u16*)(ws + OFF_H0) + (size_t)g * 2 * 4096;
  u16* h1s = (u16*)(ws + OFF_H1) + (size_t)g * 2 * 4096;
  u16* f0s = (u16*)(ws + OFF_F0) + (size_t)g * 4096;
  u16* f1s = (u16*)(ws + OFF_F1) + (size_t)g * 4096;
  float* c0ws = (float*)(ws + OFF_C0);
  float* c1ws = (float*)(ws + OFF_C1);

  __shared__ short8 sh0[16][33];             // r11 staging (proven)
  __shared__ short8 sh1[16][33];

  const int n    = 16 * w + fcol;
  const int grow = (n & 3) * HDIM + m * 16 + (n >> 2);
  short8 wh0[8], wi1[8], wh1[8];
#pragma unroll
  for (int kf = 0; kf < 8; kf++) {
    const int k0 = kf * 32 + kq * 8;
    wh0[kf] = ld_frag8(Whh0, grow, HDIM, k0, mode);
    wi1[kf] = ld_frag8(Wih1, grow, HDIM, k0, mode);
    wh1[kf] = ld_frag8(Whh1, grow, HDIM, k0, mode);
  }
  float wx[4], bb0[4], bb1[4];
#pragma unroll
  for (int gt = 0; gt < 4; gt++) {
    wx[gt]  = ld_scalar(Wih0, gt * HDIM + chq, mode);
    bb0[gt] = ld_scalar(b0,   gt * HDIM + chq, mode);
    bb1[gt] = ld_scalar(b1,   gt * HDIM + chq, mode);
  }
  float c0 = 0.f, c1 = 0.f, h0keep = 0.f, h1fin = 0.f;

  for (int t = 0; t <= S_LEN; t++) {
    const int pr = (t + 1) & 1, pw = t & 1;
    short8 a0[8], a1[8];
    float x = 0.f;
    if (t >= 1) {
      // drain pending h1 store from last tick, then deferred per-wave f1 publish
      asm volatile("s_waitcnt vmcnt(0)" ::: "memory");
      __builtin_amdgcn_sched_barrier(0);
      if (t >= 2 && lane == 0) st32(fe1g + m * 4 + w, (unsigned)(t - 1));
      // feat load overlaps the poll
      if (t < S_LEN) x = ld_scalar(feat, (long)bgl * S_LEN + t, mode);
      // hot-spin combined poll (64 per-wave flags per array)
      const unsigned* f0a = fe0g + lane;
      const unsigned* f1a = fe1g + lane;
      int spin = 0;
      if (t >= 2) {
        for (;;) {
          unsigned v0, v1;
          asm volatile("global_load_dword %0, %2, off sc0 sc1\n\t"
                       "global_load_dword %1, %3, off sc0 sc1\n\t"
                       "s_waitcnt vmcnt(0)"
                       : "=&v"(v0), "=&v"(v1) : "v"(f0a), "v"(f1a) : "memory");
          if (__all((v0 >= (unsigned)t) && (v1 >= (unsigned)(t - 1)))) break;
          if (++spin > SPIN_MAX) break;
        }
      } else {
        for (;;) {
          unsigned v0;
          asm volatile("global_load_dword %0, %1, off sc0 sc1\n\ts_waitcnt vmcnt(0)"
                       : "=&v"(v0) : "v"(f0a) : "memory");
          if (__all(v0 >= (unsigned)t)) break;
          if (++spin > SPIN_MAX) break;
        }
      }
      __builtin_amdgcn_sched_barrier(0);
      // coop load + LDS stage (r11 exact)
      short8 va0, va1, vb0, vb1;
      ld32B(h0s + pr * 4096 + tid * 16, &va0, &va1);
      if (t >= 2) ld32B(h1s + pr * 4096 + tid * 16, &vb0, &vb1);
      waitv0();
      sh0[sr][sc2] = va0; sh0[sr][sc2 + 1] = va1;
      if (t >= 2) { sh1[sr][sc2] = vb0; sh1[sr][sc2 + 1] = vb1; }
      __syncthreads();
#pragma unroll
      for (int kf = 0; kf < 8; kf++) a0[kf] = sh0[fcol][kf * 4 + kq];
      if (t >= 2) {
#pragma unroll
        for (int kf = 0; kf < 8; kf++) a1[kf] = sh1[fcol][kf * 4 + kq];
      }
    } else {
      x = ld_scalar(feat, (long)bgl * S_LEN + t, mode);
    }

    // ---- layer0 + f0 publish (global critical chain) ----
    f32x4 acc0 = {0.f, 0.f, 0.f, 0.f}, acc1 = {0.f, 0.f, 0.f, 0.f};
    if (t >= 1 && t < S_LEN) {
#pragma unroll
      for (int kf = 0; kf < 8; kf++) acc0 = mfma_bf16(wh0[kf], a0[kf], acc0);  // swapped
    }
    if (t < S_LEN) {
      const float gi = acc0[0] + x * wx[0] + bb0[0];
      const float gf = acc0[1] + x * wx[1] + bb0[1];
      const float gg = acc0[2] + x * wx[2] + bb0[2];
      const float go = acc0[3] + x * wx[3] + bb0[3];
      c0 = sigm(gf) * c0 + sigm(gi) * tanhf(gg);
      const float h0v = sigm(go) * tanhf(c0);
      h0keep = h0v;
      st16(h0s + pw * 4096 + fcol * 256 + chq, f2bf(h0v));
    }
    // hide part of h0's drain under layer1's first MFMA half
    if (t >= 1) {
#pragma unroll
      for (int kf = 0; kf < 8; kf++) acc1 = mfma_bf16(wi1[kf], a0[kf], acc1);
    }
    if (t < S_LEN) {
      asm volatile("s_waitcnt vmcnt(0)" ::: "memory");   // h0 coherent
      __builtin_amdgcn_sched_barrier(0);
      if (lane == 0) st32(fe0g + m * 4 + w, (unsigned)(t + 1));
    }
    // ---- layer1 (off the global chain) ----
    if (t >= 1) {
      if (t >= 2) {
#pragma unroll
        for (int kf = 0; kf < 8; kf++) acc1 = mfma_bf16(wh1[kf], a1[kf], acc1);
      }
      const float gi = acc1[0] + bb1[0];
      const float gf = acc1[1] + bb1[1];
      const float gg = acc1[2] + bb1[2];
      const float go = acc1[3] + bb1[3];
      c1 = sigm(gf) * c1 + sigm(gi) * tanhf(gg);
      const float h1v = sigm(go) * tanhf(c1);
      if (t < S_LEN) st16(h1s + pw * 4096 + fcol * 256 + chq, f2bf(h1v));  // no drain
      else h1fin = h1v;
    }
  }
  // handoff (plain; kernel boundary provides ordering + writeback)
  f0s[fcol * 256 + chq] = f2bf(h0keep);
  f1s[fcol * 256 + chq] = f2bf(h1fin);
  c0ws[(size_t)bgl * HDIM + chq] = c0;
  c1ws[(size_t)bgl * HDIM + chq] = c1;
}

// ============================ decoder ============================
// r11 EXACT: wg-flag epochs, phase A -> 3s+1, B -> 3s+2, C -> 3s+3.
__global__ void __launch_bounds__(256, 1)
dec_kernel(const void* __restrict__ Wih0, const void* __restrict__ Whh0, const void* __restrict__ b0,
           const void* __restrict__ Wih1, const void* __restrict__ Whh1, const void* __restrict__ b1,
           const void* __restrict__ W1, const void* __restrict__ b1h, const void* __restrict__ W2,
           const void* __restrict__ b2, char* __restrict__ ws, void* __restrict__ out) {
  const int mode = (int)*(const unsigned*)(ws + OFF_FLAG);
  const int tid  = threadIdx.x;
  const int lane = tid & 63;
  const int w    = tid >> 6;
  const int bId  = blockIdx.x;
  const int g    = (bId & 7) * 2 + ((bId >> 3) & 1);
  const int m    = bId >> 4;

  const int fcol = lane & 15;
  const int kq   = lane >> 4;
  const int chq  = m * 16 + w * 4 + kq;
  const int bgl  = g * 16 + fcol;
  const int sr   = tid >> 4;
  const int sc2  = (tid & 15) * 2;

  unsigned* fd_g = (unsigned*)(ws + OFF_FD) + g * 128;
  u16* h0s = (u16*)(ws + OFF_H0) + (size_t)g * 2 * 4096;
  u16* h1s = (u16*)(ws + OFF_H1) + (size_t)g * 2 * 4096;
  u16* f0s = (u16*)(ws + OFF_F0) + (size_t)g * 4096;
  u16* f1s = (u16*)(ws + OFF_F1) + (size_t)g * 4096;
  float* partial = (float*)(ws + OFF_PART);
  float* c0ws = (float*)(ws + OFF_C0);
  float* c1ws = (float*)(ws + OFF_C1);

  __shared__ short8 sh0[16][33];
  __shared__ short8 sh1[16][33];
  __shared__ float part[4 * 256];
  __shared__ float redv[256];
  __shared__ float xacc[256];

  const int n    = 16 * w + fcol;
  const int grow = (n & 3) * HDIM + m * 16 + (n >> 2);
  short8 wh0[8], wi1[8], wh1[8], ww1[2];
#pragma unroll
  for (int kf = 0; kf < 8; kf++) {
    const int k0 = kf * 32 + kq * 8;
    wh0[kf] = ld_frag8(Whh0, grow, HDIM, k0, mode);
    wi1[kf] = ld_frag8(Wih1, grow, HDIM, k0, mode);
    wh1[kf] = ld_frag8(Whh1, grow, HDIM, k0, mode);
  }
#pragma unroll
  for (int kf2 = 0; kf2 < 2; kf2++) {
    const int k0 = w * 64 + kf2 * 32 + kq * 8;       // K-split of head GEMM across waves
    ww1[kf2] = ld_frag8(W1, m * 16 + fcol, HDIM, k0, mode);
  }
  float wx[4], bb0[4], bb1[4];
#pragma unroll
  for (int gt = 0; gt < 4; gt++) {
    wx[gt]  = ld_scalar(Wih0, gt * HDIM + chq, mode);
    bb0[gt] = ld_scalar(b0,   gt * HDIM + chq, mode);
    bb1[gt] = ld_scalar(b1,   gt * HDIM + chq, mode);
  }
  const int hb = tid & 15, hcl = tid >> 4;           // head reduce roles
  const float b1hv = ld_scalar(b1h, m * 16 + hcl, mode);
  const float w2v  = ld_scalar(W2,  m * 16 + hcl, mode);
  const float b2v  = ld_scalar(b2, 0, mode);

  float c0 = c0ws[(size_t)bgl * HDIM + chq];
  float c1 = c1ws[(size_t)bgl * HDIM + chq];

  for (int s = 0; s < T_LEN; s++) {
    const int ppr = (s - 1) & 1, pcur = s & 1;
    // ---------- phase A: pred(s-1) gather + layer0 ----------
    float x = 0.f;
    {
      if (s > 0) pollge(fd_g, (unsigned)(3 * s));
      short8 va0, va1;
      float pv = 0.f;
      if (s > 0) {
        ld32B(h0s + ppr * 4096 + tid * 16, &va0, &va1);
        pv = ldf32(partial + (((size_t)ppr * 16 + g) * 16 + (tid >> 4)) * 16 + (tid & 15));
      } else {
        ld32B(f0s + tid * 16, &va0, &va1);
        waitv0();
      }
      sh0[sr][sc2] = va0; sh0[sr][sc2 + 1] = va1;
      if (s > 0) xacc[(tid & 15) * 16 + (tid >> 4)] = pv;
      __syncthreads();
      if (s > 0) {
#pragma unroll
        for (int j = 0; j < 16; j++) x += xacc[fcol * 16 + j];
        if (m == 0 && tid < 16)
          st_out(out, (size_t)(g * 16 + tid) * T_LEN + (s - 1), x, mode);
      }
      short8 a0[8];
#pragma unroll
      for (int kf = 0; kf < 8; kf++) a0[kf] = sh0[fcol][kf * 4 + kq];
      f32x4 acc = {0.f, 0.f, 0.f, 0.f};
#pragma unroll
      for (int kf = 0; kf < 8; kf++) acc = mfma_bf16(wh0[kf], a0[kf], acc);
      const float gi = acc[0] + x * wx[0] + bb0[0];
      const float gf = acc[1] + x * wx[1] + bb0[1];
      const float gg = acc[2] + x * wx[2] + bb0[2];
      const float go = acc[3] + x * wx[3] + bb0[3];
      c0 = sigm(gf) * c0 + sigm(gi) * tanhf(gg);
      const float h0v = sigm(go) * tanhf(c0);
      st16(h0s + pcur * 4096 + fcol * 256 + chq, f2bf(h0v));
      wg_publish(fd_g + m * 8, (unsigned)(3 * s + 1));
    }
    // ---------- phase B: layer1 ----------
    {
      pollge(fd_g, (unsigned)(3 * s + 1));
      short8 va0, va1, vb0, vb1;
      ld32B(h0s + pcur * 4096 + tid * 16, &va0, &va1);
      ld32B(((s == 0) ? f1s : (h1s + ppr * 4096)) + tid * 16, &vb0, &vb1);
      waitv0();
      sh0[sr][sc2] = va0; sh0[sr][sc2 + 1] = va1;
      sh1[sr][sc2] = vb0; sh1[sr][sc2 + 1] = vb1;
      __syncthreads();
      short8 ay[8], a1[8];
#pragma unroll
      for (int kf = 0; kf < 8; kf++) {
        ay[kf] = sh0[fcol][kf * 4 + kq];
        a1[kf] = sh1[fcol][kf * 4 + kq];
      }
      f32x4 acc = {0.f, 0.f, 0.f, 0.f};
#pragma unroll
      for (int kf = 0; kf < 8; kf++) {
        acc = mfma_bf16(wi1[kf], ay[kf], acc);
        acc = mfma_bf16(wh1[kf], a1[kf], acc);
      }
      const float gi = acc[0] + bb1[0];
      const float gf = acc[1] + bb1[1];
      const float gg = acc[2] + bb1[2];
      const float go = acc[3] + bb1[3];
      c1 = sigm(gf) * c1 + sigm(gi) * tanhf(gg);
      const float h1v = sigm(go) * tanhf(c1);
      st16(h1s + pcur * 4096 + fcol * 256 + chq, f2bf(h1v));
      wg_publish(fd_g + m * 8, (unsigned)(3 * s + 2));
    }
    // ---------- phase C: head (Linear->ReLU->Linear), K-split across waves ----------
    {
      pollge(fd_g, (unsigned)(3 * s + 2));
      short8 ah[2];
      issue2(h1s + pcur * 4096 + fcol * 256 + w * 64 + kq * 8, ah);
      waitv0();
      f32x4 acc = {0.f, 0.f, 0.f, 0.f};
      acc = mfma_bf16(ww1[0], ah[0], acc);
      acc = mfma_bf16(ww1[1], ah[1], acc);
      // acc[i] = hidden[hch m*16 + 4kq+i][batch fcol] (K-slice w)
      *(f32x4*)&part[w * 256 + fcol * 16 + kq * 4] = acc;
      __syncthreads();
      float hid = part[0 * 256 + hb * 16 + hcl] + part[1 * 256 + hb * 16 + hcl]
                + part[2 * 256 + hb * 16 + hcl] + part[3 * 256 + hb * 16 + hcl] + b1hv;
      hid = fmaxf(hid, 0.f);
      redv[hcl * 16 + hb] = hid * w2v;
      __syncthreads();
      if (tid < 16) {
        float a = (m == 0) ? b2v : 0.f;
#pragma unroll
        for (int cc = 0; cc < 16; cc++) a += redv[cc * 16 + tid];
        stf32(partial + (((size_t)pcur * 16 + g) * 16 + m) * 16 + tid, a);
      }
      wg_publish(fd_g + m * 8, (unsigned)(3 * s + 3));
    }
  }
  // final output column: pred(T-1) from partials of step T-1 (parity 1)
  if (m == 0) {
    pollge(fd_g, (unsigned)(3 * T_LEN));
    const float pv = ldf32(partial + (((size_t)1 * 16 + g) * 16 + (tid >> 4)) * 16 + (tid & 15));
    xacc[(tid & 15) * 16 + (tid >> 4)] = pv;
    __syncthreads();
    if (tid < 16) {
      float x = 0.f;
#pragma unroll
      for (int j = 0; j < 16; j++) x += xacc[tid * 16 + j];
      st_out(out, (size_t)(g * 16 + tid) * T_LEN + (T_LEN - 1), x, mode);
    }
  }
}

extern "C" void kernel_launch(void* const* d_in, const int* in_sizes, int n_in,
                              void* d_out, int out_size, void* d_ws, size_t ws_size,
                              hipStream_t stream) {
  char* ws = (char*)d_ws;
  // zero flags + partials every launch (epoch 0 == empty; replay-safe)
  hipMemsetAsync(ws, 0, ZERO_END, stream);
  detect_mode<<<1, 64, 0, stream>>>((const unsigned*)d_in[0], (unsigned*)(ws + OFF_FLAG));
  enc_kernel<<<256, 256, 0, stream>>>(d_in[0], d_in[1], d_in[2], d_in[3],
                                      d_in[4], d_in[5], d_in[6], ws);
  dec_kernel<<<256, 256, 0, stream>>>(d_in[7], d_in[8], d_in[9], d_in[10], d_in[11], d_in[12],
                                      d_in[13], d_in[14], d_in[15], d_in[16], ws, d_out);
}

// Round 15
// 2702.834 us; speedup vs baseline: 1.8822x; 1.8822x over previous
//
#include <hip/hip_runtime.h>

// Seq2Seq LSTM forecaster: H=256, B=256, S=672, T=96.
// Round 15: r11 (3.20ms best) + ONE mechanism: half the sync width.
//   - Encoder: 128 wgs of 512 threads = 16 groups x 8 members. Each wg fuses TWO
//     r11 channel-shards (waves 0-3 -> shard m*2, waves 4-7 -> shard m*2+1); every
//     wave runs r11's exact per-wave code (wl=w&3, sh=m*2+(w>>2) substitution).
//   - Group sync: 8 flags (was 16) -> poll reads 8, straggler max() over 8, flag
//     traffic halved. Publish = per-thread drain -> 512-thread barrier -> tid0 store.
//   - Slab layout/staging/MFMA mapping/epochs/parities: r11 verbatim.
//   - r14 lesson applied: single drain covering both layers' stores, s_sleep poll.
//   - Decoder: r11 EXACT (256 wgs x 256 thr, 16-wg flag protocol, 0.63ms).

#define S_LEN 672
#define T_LEN 96
#define HDIM  256
#define SPIN_MAX (1 << 14)

typedef short short8 __attribute__((ext_vector_type(8)));
typedef float f32x4  __attribute__((ext_vector_type(4)));
typedef unsigned short u16;

// ---- workspace layout (bytes) ----
#define OFF_FLAG 0                                  // dtype mode flag
#define OFF_FE   1024                               // enc flags: [16g][8wg] u32 @32B stride
#define OFF_FD   (OFF_FE + 16*8*32)                 // dec flags: [16g][16wg] u32 @32B stride
#define OFF_PART (OFF_FD + 16*16*32)                // f32 [2][16g][16m][16b]
#define ZERO_END (OFF_PART + 2*16*256*4)
#define OFF_H0   ZERO_END                           // u16 [16g][2][16b][256ch]
#define OFF_H1   (OFF_H0 + 16*2*4096*2)
#define OFF_F0   (OFF_H1 + 16*2*4096*2)             // u16 [16g][16b][256ch] h0 final
#define OFF_F1   (OFF_F0 + 16*4096*2)               // u16 h1 final
#define OFF_C0   (OFF_F1 + 16*4096*2)               // f32 [256][256]
#define OFF_C1   (OFF_C0 + 256*256*4)

__device__ __forceinline__ unsigned short f2bf(float f) {
  unsigned u = __float_as_uint(f);
  u += 0x7FFFu + ((u >> 16) & 1u);
  return (unsigned short)(u >> 16);
}
__device__ __forceinline__ float bf2f(unsigned short s) {
  return __uint_as_float(((unsigned)s) << 16);
}
__device__ __forceinline__ float ld_scalar(const void* p, long idx, int mode) {
  if (mode) return bf2f(((const u16*)p)[idx]);
  return ((const float*)p)[idx];
}
__device__ __forceinline__ short8 ld_frag8(const void* p, long row, long ld, long k0, int mode) {
  if (mode) {
    return *(const short8*)((const u16*)p + row * ld + k0);
  } else {
    const float* f = (const float*)p + row * ld + k0;
    short8 r;
#pragma unroll
    for (int i = 0; i < 8; i++) r[i] = (short)f2bf(f[i]);
    return r;
  }
}
__device__ __forceinline__ void st_out(void* out, size_t idx, float v, int mode) {
  if (mode) ((u16*)out)[idx] = f2bf(v);
  else      ((float*)out)[idx] = v;
}
__device__ __forceinline__ float sigm(float x) { return 1.f / (1.f + __expf(-x)); }

__device__ __forceinline__ f32x4 mfma_bf16(short8 a, short8 b, f32x4 c) {
  return __builtin_amdgcn_mfma_f32_16x16x32_bf16(a, b, c, 0, 0, 0);
}

// ---- system-scope data plane (sc0 sc1; r6/r7/r11-proven) ----
__device__ __forceinline__ void ld16B(const u16* b, short8* c0) {
  asm volatile("global_load_dwordx4 %0, %1, off sc0 sc1"
               : "=&v"(*c0) : "v"(b) : "memory");
}
__device__ __forceinline__ void ld32B(const u16* b, short8* c0, short8* c1) {
  asm volatile(
    "global_load_dwordx4 %0, %2, off sc0 sc1\n\t"
    "global_load_dwordx4 %1, %2, off offset:16 sc0 sc1"
    : "=&v"(*c0), "=&v"(*c1) : "v"(b) : "memory");
}
__device__ __forceinline__ void issue2(const u16* base, short8* t) {
  asm volatile(
    "global_load_dwordx4 %0, %2, off sc0 sc1\n\t"
    "global_load_dwordx4 %1, %2, off offset:64 sc0 sc1"
    : "=&v"(t[0]), "=&v"(t[1]) : "v"(base) : "memory");
}
__device__ __forceinline__ void st16(u16* p, unsigned short v) {
  asm volatile("global_store_short %0, %1, off sc0 sc1"
               :: "v"(p), "v"((unsigned)v) : "memory");
}
__device__ __forceinline__ void stf32(float* p, float v) {
  asm volatile("global_store_dword %0, %1, off sc0 sc1" :: "v"(p), "v"(v) : "memory");
}
__device__ __forceinline__ float ldf32(const float* p) {
  float v;
  asm volatile("global_load_dword %0, %1, off sc0 sc1\n\ts_waitcnt vmcnt(0)"
               : "=&v"(v) : "v"(p) : "memory");
  __builtin_amdgcn_sched_barrier(0);
  return v;
}
__device__ __forceinline__ void waitv0() {
  asm volatile("s_waitcnt vmcnt(0)" ::: "memory");
  __builtin_amdgcn_sched_barrier(0);
}

// ---- control plane: plain sc0 sc1 epoch flags ----
__device__ __forceinline__ void wg_publish(unsigned* fa, unsigned e) {
  asm volatile("s_waitcnt vmcnt(0)" ::: "memory");
  __syncthreads();
  if (threadIdx.x == 0)
    asm volatile("global_store_dword %0, %1, off sc0 sc1" :: "v"(fa), "v"(e) : "memory");
}
__device__ __forceinline__ void pollge8(const unsigned* flags, unsigned E) {
  const unsigned* addr = flags + (threadIdx.x & 7) * 8;
  int spin = 0;
  for (;;) {
    unsigned v;
    asm volatile("global_load_dword %0, %1, off sc0 sc1\n\ts_waitcnt vmcnt(0)"
                 : "=&v"(v) : "v"(addr) : "memory");
    if (__all(v >= E)) break;
    if (++spin > SPIN_MAX) break;
    __builtin_amdgcn_s_sleep(1);
  }
  __builtin_amdgcn_sched_barrier(0);
}
__device__ __forceinline__ void pollge16(const unsigned* flags, unsigned E) {
  const unsigned* addr = flags + (threadIdx.x & 15) * 8;
  int spin = 0;
  for (;;) {
    unsigned v;
    asm volatile("global_load_dword %0, %1, off sc0 sc1\n\ts_waitcnt vmcnt(0)"
                 : "=&v"(v) : "v"(addr) : "memory");
    if (__all(v >= E)) break;
    if (++spin > SPIN_MAX) break;
    __builtin_amdgcn_s_sleep(1);
  }
  __builtin_amdgcn_sched_barrier(0);
}

// ---- dtype detector ----
__global__ void detect_mode(const unsigned* __restrict__ feat, unsigned* __restrict__ flag) {
  const int t = threadIdx.x;
  int cnt = 0;
#pragma unroll
  for (int i = 0; i < 8; i++) {
    const unsigned wv = feat[t * 8 + i];
    const unsigned e = (wv >> 7) & 0xFFu;
    cnt += (e >= 100u && e <= 130u) ? 1 : 0;
  }
#pragma unroll
  for (int o = 32; o > 0; o >>= 1) cnt += __shfl_down(cnt, o, 64);
  if (t == 0) flag[0] = (cnt >= 256) ? 1u : 0u;
}

// ============================ encoder (512 threads, 2 shards/wg) ============================
// Tick t: layer0 step t (t<672), layer1 step t-1 (t>=1). Per-wg flag after tick
// t = t+1 (covers all 8 waves' h0(t)/h1(t-1) stores, drained). Tick-t reads poll
// >= t over 8 wg-flags. Slab parity: h(t) at t&1; tick-t reads at (t+1)&1.
__global__ void __launch_bounds__(512, 1)
enc_kernel(const void* __restrict__ feat,
           const void* __restrict__ Wih0, const void* __restrict__ Whh0, const void* __restrict__ b0,
           const void* __restrict__ Wih1, const void* __restrict__ Whh1, const void* __restrict__ b1,
           char* __restrict__ ws) {
  const int mode = (int)*(const unsigned*)(ws + OFF_FLAG);
  const int tid  = threadIdx.x;
  const int lane = tid & 63;
  const int w    = tid >> 6;                 // wave 0..7
  const int wl   = w & 3;                    // wave within half (r11's w)
  const int bId  = blockIdx.x;               // 0..127
  const int g    = (bId & 7) * 2 + ((bId >> 3) & 1);
  const int m    = bId >> 4;                 // member 0..7
  const int sh   = m * 2 + (w >> 2);         // channel shard 0..15 (r11's m)

  const int fcol = lane & 15;                // batch row
  const int kq   = lane >> 4;                // k-quarter / channel sub-index
  const int chq  = sh * 16 + wl * 4 + kq;    // this lane's pointwise channel
  const int bgl  = g * 16 + fcol;
  const int sr   = tid >> 5;                 // stage row (batch), 512thr x 16B
  const int scc  = tid & 31;                 // stage col (short8 chunk)

  unsigned* fe_g = (unsigned*)(ws + OFF_FE) + g * 64;     // 8 flags @ stride 8 u32
  u16* h0s = (u16*)(ws + OFF_H0) + (size_t)g * 2 * 4096;
  u16* h1s = (u16*)(ws + OFF_H1) + (size_t)g * 2 * 4096;
  u16* f0s = (u16*)(ws + OFF_F0) + (size_t)g * 4096;
  u16* f1s = (u16*)(ws + OFF_F1) + (size_t)g * 4096;
  float* c0ws = (float*)(ws + OFF_C0);
  float* c1ws = (float*)(ws + OFF_C1);

  __shared__ short8 sh0[16][33];             // r11 staging (proven)
  __shared__ short8 sh1[16][33];

  // weight fragments: wave owns gate-cols n = 16*wl + fcol of shard sh
  const int n    = 16 * wl + fcol;
  const int grow = (n & 3) * HDIM + sh * 16 + (n >> 2);
  short8 wh0[8], wi1[8], wh1[8];
#pragma unroll
  for (int kf = 0; kf < 8; kf++) {
    const int k0 = kf * 32 + kq * 8;
    wh0[kf] = ld_frag8(Whh0, grow, HDIM, k0, mode);
    wi1[kf] = ld_frag8(Wih1, grow, HDIM, k0, mode);
    wh1[kf] = ld_frag8(Whh1, grow, HDIM, k0, mode);
  }
  float wx[4], bb0[4], bb1[4];
#pragma unroll
  for (int gt = 0; gt < 4; gt++) {
    wx[gt]  = ld_scalar(Wih0, gt * HDIM + chq, mode);
    bb0[gt] = ld_scalar(b0,   gt * HDIM + chq, mode);
    bb1[gt] = ld_scalar(b1,   gt * HDIM + chq, mode);
  }
  float c0 = 0.f, c1 = 0.f, h0keep = 0.f, h1fin = 0.f;

  for (int t = 0; t <= S_LEN; t++) {
    const int pr = (t + 1) & 1, pw = t & 1;
    short8 a0[8], a1[8];
    if (t >= 1) {
      pollge8(fe_g, (unsigned)t);
      short8 va, vb;
      ld16B(h0s + pr * 4096 + tid * 8, &va);
      if (t >= 2) ld16B(h1s + pr * 4096 + tid * 8, &vb);
      waitv0();
      sh0[sr][scc] = va;
      if (t >= 2) sh1[sr][scc] = vb;
      __syncthreads();
#pragma unroll
      for (int kf = 0; kf < 8; kf++) a0[kf] = sh0[fcol][kf * 4 + kq];
      if (t >= 2) {
#pragma unroll
        for (int kf = 0; kf < 8; kf++) a1[kf] = sh1[fcol][kf * 4 + kq];
      }
    }

    f32x4 acc0 = {0.f, 0.f, 0.f, 0.f}, acc1 = {0.f, 0.f, 0.f, 0.f};
    if (t >= 1 && t < S_LEN) {
#pragma unroll
      for (int kf = 0; kf < 8; kf++) acc0 = mfma_bf16(wh0[kf], a0[kf], acc0);  // swapped
    }
    if (t >= 1) {
#pragma unroll
      for (int kf = 0; kf < 8; kf++) acc1 = mfma_bf16(wi1[kf], a0[kf], acc1);
      if (t >= 2) {
#pragma unroll
        for (int kf = 0; kf < 8; kf++) acc1 = mfma_bf16(wh1[kf], a1[kf], acc1);
      }
    }
    // pointwise: acc[i] = gate i of (chq, batch fcol)
    if (t < S_LEN) {
      const float x = ld_scalar(feat, (long)bgl * S_LEN + t, mode);
      const float gi = acc0[0] + x * wx[0] + bb0[0];
      const float gf = acc0[1] + x * wx[1] + bb0[1];
      const float gg = acc0[2] + x * wx[2] + bb0[2];
      const float go = acc0[3] + x * wx[3] + bb0[3];
      c0 = sigm(gf) * c0 + sigm(gi) * tanhf(gg);
      const float h0v = sigm(go) * tanhf(c0);
      h0keep = h0v;
      st16(h0s + pw * 4096 + fcol * 256 + chq, f2bf(h0v));
    }
    if (t >= 1) {
      const float gi = acc1[0] + bb1[0];
      const float gf = acc1[1] + bb1[1];
      const float gg = acc1[2] + bb1[2];
      const float go = acc1[3] + bb1[3];
      c1 = sigm(gf) * c1 + sigm(gi) * tanhf(gg);
      const float h1v = sigm(go) * tanhf(c1);
      if (t < S_LEN) st16(h1s + pw * 4096 + fcol * 256 + chq, f2bf(h1v));
      else h1fin = h1v;
    }
    wg_publish(fe_g + m * 8, (unsigned)(t + 1));
  }
  // handoff (plain; kernel boundary provides ordering + writeback)
  f0s[fcol * 256 + chq] = f2bf(h0keep);
  f1s[fcol * 256 + chq] = f2bf(h1fin);
  c0ws[(size_t)bgl * HDIM + chq] = c0;
  c1ws[(size_t)bgl * HDIM + chq] = c1;
}

// ============================ decoder (r11 EXACT) ============================
// Per-wg flag epochs: phase A of step s -> 3s+1, B -> 3s+2, C -> 3s+3.
__global__ void __launch_bounds__(256, 1)
dec_kernel(const void* __restrict__ Wih0, const void* __restrict__ Whh0, const void* __restrict__ b0,
           const void* __restrict__ Wih1, const void* __restrict__ Whh1, const void* __restrict__ b1,
           const void* __restrict__ W1, const void* __restrict__ b1h, const void* __restrict__ W2,
           const void* __restrict__ b2, char* __restrict__ ws, void* __restrict__ out) {
  const int mode = (int)*(const unsigned*)(ws + OFF_FLAG);
  const int tid  = threadIdx.x;
  const int lane = tid & 63;
  const int w    = tid >> 6;
  const int bId  = blockIdx.x;
  const int g    = (bId & 7) * 2 + ((bId >> 3) & 1);
  const int m    = bId >> 4;

  const int fcol = lane & 15;
  const int kq   = lane >> 4;
  const int chq  = m * 16 + w * 4 + kq;
  const int bgl  = g * 16 + fcol;
  const int sr   = tid >> 4;
  const int sc2  = (tid & 15) * 2;

  unsigned* fd_g = (unsigned*)(ws + OFF_FD) + g * 128;
  u16* h0s = (u16*)(ws + OFF_H0) + (size_t)g * 2 * 4096;
  u16* h1s = (u16*)(ws + OFF_H1) + (size_t)g * 2 * 4096;
  u16* f0s = (u16*)(ws + OFF_F0) + (size_t)g * 4096;
  u16* f1s = (u16*)(ws + OFF_F1) + (size_t)g * 4096;
  float* partial = (float*)(ws + OFF_PART);
  float* c0ws = (float*)(ws + OFF_C0);
  float* c1ws = (float*)(ws + OFF_C1);

  __shared__ short8 sh0[16][33];
  __shared__ short8 sh1[16][33];
  __shared__ float part[4 * 256];
  __shared__ float redv[256];
  __shared__ float xacc[256];

  const int n    = 16 * w + fcol;
  const int grow = (n & 3) * HDIM + m * 16 + (n >> 2);
  short8 wh0[8], wi1[8], wh1[8], ww1[2];
#pragma unroll
  for (int kf = 0; kf < 8; kf++) {
    const int k0 = kf * 32 + kq * 8;
    wh0[kf] = ld_frag8(Whh0, grow, HDIM, k0, mode);
    wi1[kf] = ld_frag8(Wih1, grow, HDIM, k0, mode);
    wh1[kf] = ld_frag8(Whh1, grow, HDIM, k0, mode);
  }
#pragma unroll
  for (int kf2 = 0; kf2 < 2; kf2++) {
    const int k0 = w * 64 + kf2 * 32 + kq * 8;       // K-split of head GEMM across waves
    ww1[kf2] = ld_frag8(W1, m * 16 + fcol, HDIM, k0, mode);
  }
  float wx[4], bb0[4], bb1[4];
#pragma unroll
  for (int gt = 0; gt < 4; gt++) {
    wx[gt]  = ld_scalar(Wih0, gt * HDIM + chq, mode);
    bb0[gt] = ld_scalar(b0,   gt * HDIM + chq, mode);
    bb1[gt] = ld_scalar(b1,   gt * HDIM + chq, mode);
  }
  const int hb = tid & 15, hcl = tid >> 4;           // head reduce roles
  const float b1hv = ld_scalar(b1h, m * 16 + hcl, mode);
  const float w2v  = ld_scalar(W2,  m * 16 + hcl, mode);
  const float b2v  = ld_scalar(b2, 0, mode);

  float c0 = c0ws[(size_t)bgl * HDIM + chq];
  float c1 = c1ws[(size_t)bgl * HDIM + chq];

  for (int s = 0; s < T_LEN; s++) {
    const int ppr = (s - 1) & 1, pcur = s & 1;
    // ---------- phase A: pred(s-1) gather + layer0 ----------
    float x = 0.f;
    {
      if (s > 0) pollge16(fd_g, (unsigned)(3 * s));
      short8 va0, va1;
      float pv = 0.f;
      if (s > 0) {
        ld32B(h0s + ppr * 4096 + tid * 16, &va0, &va1);
        pv = ldf32(partial + (((size_t)ppr * 16 + g) * 16 + (tid >> 4)) * 16 + (tid & 15));
      } else {
        ld32B(f0s + tid * 16, &va0, &va1);
        waitv0();
      }
      sh0[sr][sc2] = va0; sh0[sr][sc2 + 1] = va1;
      if (s > 0) xacc[(tid & 15) * 16 + (tid >> 4)] = pv;
      __syncthreads();
      if (s > 0) {
#pragma unroll
        for (int j = 0; j < 16; j++) x += xacc[fcol * 16 + j];
        if (m == 0 && tid < 16)
          st_out(out, (size_t)(g * 16 + tid) * T_LEN + (s - 1), x, mode);
      }
      short8 a0[8];
#pragma unroll
      for (int kf = 0; kf < 8; kf++) a0[kf] = sh0[fcol][kf * 4 + kq];
      f32x4 acc = {0.f, 0.f, 0.f, 0.f};
#pragma unroll
      for (int kf = 0; kf < 8; kf++) acc = mfma_bf16(wh0[kf], a0[kf], acc);
      const float gi = acc[0] + x * wx[0] + bb0[0];
      const float gf = acc[1] + x * wx[1] + bb0[1];
      const float gg = acc[2] + x * wx[2] + bb0[2];
      const float go = acc[3] + x * wx[3] + bb0[3];
      c0 = sigm(gf) * c0 + sigm(gi) * tanhf(gg);
      const float h0v = sigm(go) * tanhf(c0);
      st16(h0s + pcur * 4096 + fcol * 256 + chq, f2bf(h0v));
      wg_publish(fd_g + m * 8, (unsigned)(3 * s + 1));
    }
    // ---------- phase B: layer1 ----------
    {
      pollge16(fd_g, (unsigned)(3 * s + 1));
      short8 va0, va1, vb0, vb1;
      ld32B(h0s + pcur * 4096 + tid * 16, &va0, &va1);
      ld32B(((s == 0) ? f1s : (h1s + ppr * 4096)) + tid * 16, &vb0, &vb1);
      waitv0();
      sh0[sr][sc2] = va0; sh0[sr][sc2 + 1] = va1;
      sh1[sr][sc2] = vb0; sh1[sr][sc2 + 1] = vb1;
      __syncthreads();
      short8 ay[8], a1[8];
#pragma unroll
      for (int kf = 0; kf < 8; kf++) {
        ay[kf] = sh0[fcol][kf * 4 + kq];
        a1[kf] = sh1[fcol][kf * 4 + kq];
      }
      f32x4 acc = {0.f, 0.f, 0.f, 0.f};
#pragma unroll
      for (int kf = 0; kf < 8; kf++) {
        acc = mfma_bf16(wi1[kf], ay[kf], acc);
        acc = mfma_bf16(wh1[kf], a1[kf], acc);
      }
      const float gi = acc[0] + bb1[0];
      const float gf = acc[1] + bb1[1];
      const float gg = acc[2] + bb1[2];
      const float go = acc[3] + bb1[3];
      c1 = sigm(gf) * c1 + sigm(gi) * tanhf(gg);
      const float h1v = sigm(go) * tanhf(c1);
      st16(h1s + pcur * 4096 + fcol * 256 + chq, f2bf(h1v));
      wg_publish(fd_g + m * 8, (unsigned)(3 * s + 2));
    }
    // ---------- phase C: head (Linear->ReLU->Linear), K-split across waves ----------
    {
      pollge16(fd_g, (unsigned)(3 * s + 2));
      short8 ah[2];
      issue2(h1s + pcur * 4096 + fcol * 256 + w * 64 + kq * 8, ah);
      waitv0();
      f32x4 acc = {0.f, 0.f, 0.f, 0.f};
      acc = mfma_bf16(ww1[0], ah[0], acc);
      acc = mfma_bf16(ww1[1], ah[1], acc);
      // acc[i] = hidden[hch m*16 + 4kq+i][batch fcol] (K-slice w)
      *(f32x4*)&part[w * 256 + fcol * 16 + kq * 4] = acc;
      __syncthreads();
      float hid = part[0 * 256 + hb * 16 + hcl] + part[1 * 256 + hb * 16 + hcl]
                + part[2 * 256 + hb * 16 + hcl] + part[3 * 256 + hb * 16 + hcl] + b1hv;
      hid = fmaxf(hid, 0.f);
      redv[hcl * 16 + hb] = hid * w2v;
      __syncthreads();
      if (tid < 16) {
        float a = (m == 0) ? b2v : 0.f;
#pragma unroll
        for (int cc = 0; cc < 16; cc++) a += redv[cc * 16 + tid];
        stf32(partial + (((size_t)pcur * 16 + g) * 16 + m) * 16 + tid, a);
      }
      wg_publish(fd_g + m * 8, (unsigned)(3 * s + 3));
    }
  }
  // final output column: pred(T-1) from partials of step T-1 (parity 1)
  if (m == 0) {
    pollge16(fd_g, (unsigned)(3 * T_LEN));
    const float pv = ldf32(partial + (((size_t)1 * 16 + g) * 16 + (tid >> 4)) * 16 + (tid & 15));
    xacc[(tid & 15) * 16 + (tid >> 4)] = pv;
    __syncthreads();
    if (tid < 16) {
      float x = 0.f;
#pragma unroll
      for (int j = 0; j < 16; j++) x += xacc[tid * 16 + j];
      st_out(out, (size_t)(g * 16 + tid) * T_LEN + (T_LEN - 1), x, mode);
    }
  }
}

extern "C" void kernel_launch(void* const* d_in, const int* in_sizes, int n_in,
                              void* d_out, int out_size, void* d_ws, size_t ws_size,
                              hipStream_t stream) {
  char* ws = (char*)d_ws;
  // zero flags + partials every launch (epoch 0 == empty; replay-safe)
  hipMemsetAsync(ws, 0, ZERO_END, stream);
  detect_mode<<<1, 64, 0, stream>>>((const unsigned*)d_in[0], (unsigned*)(ws + OFF_FLAG));
  enc_kernel<<<128, 512, 0, stream>>>(d_in[0], d_in[1], d_in[2], d_in[3],
                                      d_in[4], d_in[5], d_in[6], ws);
  dec_kernel<<<256, 256, 0, stream>>>(d_in[7], d_in[8], d_in[9], d_in[10], d_in[11], d_in[12],
                                      d_in[13], d_in[14], d_in[15], d_in[16], ws, d_out);
}